// Round 1
// baseline (76.763 us; speedup 1.0000x reference)
//
#include <hip/hip_runtime.h>

#define B_SZ 256
#define RNODES 1152
#define CIN 8
#define COUT 16
#define NCAPS 10
#define KDIM (RNODES*CIN)        // 9216
#define NCOL (NCAPS*COUT)        // 160
#define WSTRIDE (KDIM*COUT)      // 147456 floats per capsule

#define LROW 40                  // 32 k + 8 pad (ushorts) -> 80B rows, 16B-aligned
#define XROWS 64
#define WOFF (XROWS*LROW)        // 2560
#define BUFSZ (WOFF + NCOL*LROW) // 8960 ushorts = 17920 B per buffer

using bf16x8 = __attribute__((ext_vector_type(8))) short;
using f32x4  = __attribute__((ext_vector_type(4))) float;

__device__ __forceinline__ unsigned short f2bf(float f) {
  unsigned int u = __builtin_bit_cast(unsigned int, f);
  u += 0x7FFFu + ((u >> 16) & 1u);   // round-to-nearest-even
  return (unsigned short)(u >> 16);
}

__global__ __launch_bounds__(256) void caps_gemm(const float* __restrict__ x,
                                                 const float* __restrict__ W,
                                                 float* __restrict__ ws) {
  __shared__ unsigned short lds[2][BUFSZ];   // 35840 B total (double buffer)
  const int tid = threadIdx.x;
  const int bid = blockIdx.x;
  const int mt  = bid & 3;          // M-tile (64 rows of b)
  const int ks  = bid >> 2;         // K-split 0..63
  const int b0  = mt * 64;

  int step0, nsteps;
  if (ks < 32) { step0 = ks * 5;              nsteps = 5; }
  else         { step0 = 160 + (ks - 32) * 4; nsteps = 4; }
  const int k0 = step0 * 32;

  // staging decode: x -> 512 float4/step (2 per thread), W -> 1280 float4/step (5 per thread)
  const int xrow0 = tid >> 3;          // + 32*j
  const int xf4   = (tid & 7) * 4;     // float offset inside the 32-k slice

  f32x4 acc[NCAPS];
#pragma unroll
  for (int i = 0; i < NCAPS; ++i) acc[i] = (f32x4){0.f, 0.f, 0.f, 0.f};

  float4 px[2];
  float4 pw[5];

  // prefetch step 0
  {
    const int kg = k0;
#pragma unroll
    for (int j = 0; j < 2; ++j) {
      const int row = xrow0 + j * 32;
      px[j] = *(const float4*)(x + (size_t)(b0 + row) * KDIM + kg + xf4);
    }
#pragma unroll
    for (int j = 0; j < 5; ++j) {
      const int idx = tid + 256 * j;
      const int c4 = idx >> 5, kl = idx & 31;
      const int n = c4 >> 2, o4 = (c4 & 3) << 2;
      pw[j] = *(const float4*)(W + (size_t)n * WSTRIDE + (size_t)(kg + kl) * COUT + o4);
    }
  }

  const int lane = tid & 63;
  const int wv   = tid >> 6;       // wave 0..3 -> 16-row sub-tile
  const int q    = lane >> 4;      // k-quad
  const int m16  = lane & 15;
  const int a_off = (wv * 16 + m16) * LROW + q * 8;

  for (int s = 0; s < nsteps; ++s) {
    unsigned short* buf = lds[s & 1];

    // ---- write staged data (bf16) to LDS ----
#pragma unroll
    for (int j = 0; j < 2; ++j) {
      const int row = xrow0 + j * 32;
      ushort4 v;
      v.x = f2bf(px[j].x); v.y = f2bf(px[j].y);
      v.z = f2bf(px[j].z); v.w = f2bf(px[j].w);
      *(ushort4*)&buf[row * LROW + xf4] = v;
    }
#pragma unroll
    for (int j = 0; j < 5; ++j) {
      const int idx = tid + 256 * j;
      const int c4 = idx >> 5, kl = idx & 31;
      const int n = c4 >> 2, o4 = (c4 & 3) << 2;
      const int cbase = WOFF + (n * COUT + o4) * LROW + kl;
      buf[cbase + 0 * LROW] = f2bf(pw[j].x);   // transpose: [col][k]
      buf[cbase + 1 * LROW] = f2bf(pw[j].y);
      buf[cbase + 2 * LROW] = f2bf(pw[j].z);
      buf[cbase + 3 * LROW] = f2bf(pw[j].w);
    }
    __syncthreads();

    // ---- issue next step's global loads; they fly under the MFMA phase ----
    if (s + 1 < nsteps) {
      const int kg = k0 + (s + 1) * 32;
#pragma unroll
      for (int j = 0; j < 2; ++j) {
        const int row = xrow0 + j * 32;
        px[j] = *(const float4*)(x + (size_t)(b0 + row) * KDIM + kg + xf4);
      }
#pragma unroll
      for (int j = 0; j < 5; ++j) {
        const int idx = tid + 256 * j;
        const int c4 = idx >> 5, kl = idx & 31;
        const int n = c4 >> 2, o4 = (c4 & 3) << 2;
        pw[j] = *(const float4*)(W + (size_t)n * WSTRIDE + (size_t)(kg + kl) * COUT + o4);
      }
    }

    // ---- MFMA phase: one A-frag, 10 B-frags (one per capsule) ----
    bf16x8 a = *(const bf16x8*)&buf[a_off];
#pragma unroll
    for (int nt = 0; nt < NCAPS; ++nt) {
      bf16x8 bfrag = *(const bf16x8*)&buf[WOFF + (nt * COUT + m16) * LROW + q * 8];
      acc[nt] = __builtin_amdgcn_mfma_f32_16x16x32_bf16(a, bfrag, acc[nt], 0, 0, 0);
    }
  }

  // ---- epilogue: atomic split-K reduction into ws[(n*256+b)*16+o] ----
  // C/D layout: col = lane&15 (= o), row = q*4 + reg (b within wave tile)
  const int brow = b0 + wv * 16 + q * 4;
#pragma unroll
  for (int nt = 0; nt < NCAPS; ++nt) {
#pragma unroll
    for (int r = 0; r < 4; ++r) {
      atomicAdd(&ws[((nt << 8) + (brow + r)) * COUT + m16], acc[nt][r]);
    }
  }
}

__global__ __launch_bounds__(256) void caps_squash(const float* __restrict__ ws,
                                                   float* __restrict__ out) {
  const int idx = blockIdx.x * 256 + threadIdx.x;   // 40960 total
  float s = ws[idx] * (1.0f / (float)RNODES);
  float sq = s * s;
  sq += __shfl_xor(sq, 1);
  sq += __shfl_xor(sq, 2);
  sq += __shfl_xor(sq, 4);
  sq += __shfl_xor(sq, 8);
  // v = s * sqrt(sq) / (1 + sq)
  out[idx] = s * sqrtf(sq) / (1.0f + sq);
}

extern "C" void kernel_launch(void* const* d_in, const int* in_sizes, int n_in,
                              void* d_out, int out_size, void* d_ws, size_t ws_size,
                              hipStream_t stream) {
  const float* x = (const float*)d_in[0];   // [256,1152,8] fp32
  const float* W = (const float*)d_in[1];   // [10,1152,8,16] fp32
  float* ws  = (float*)d_ws;                // 40960 fp32 accumulators
  float* out = (float*)d_out;               // 40960 fp32

  hipMemsetAsync(ws, 0, NCAPS * B_SZ * COUT * sizeof(float), stream);
  caps_gemm<<<dim3(256), dim3(256), 0, stream>>>(x, W, ws);
  caps_squash<<<dim3(NCAPS * B_SZ * COUT / 256), dim3(256), 0, stream>>>(ws, out);
}